// Round 2
// baseline (421.448 us; speedup 1.0000x reference)
//
#include <hip/hip_runtime.h>
#include <stdint.h>

#define IN_F  4096
#define OUT_F 4096

#define BM 128
#define BN 128
#define BK 64

typedef __attribute__((ext_vector_type(8))) short bf16x8;
typedef __attribute__((ext_vector_type(4))) float f32x4;
typedef __attribute__((ext_vector_type(8))) unsigned short u16x8;

__device__ __forceinline__ unsigned short f2bf(float f) {
  union { float f; unsigned int u; } v; v.f = f;
  return (unsigned short)((v.u + 0x7FFFu + ((v.u >> 16) & 1u)) >> 16);
}

__device__ __forceinline__ void gload_lds16(void* lds, const void* g) {
  __builtin_amdgcn_global_load_lds((const __attribute__((address_space(1))) void*)g,
                                   (__attribute__((address_space(3))) void*)lds,
                                   16u, 0, 0u);
}

// ---------------- prep kernels ----------------

__global__ void cvt_x_kernel(const float* __restrict__ x,
                             unsigned short* __restrict__ o, long n8) {
  long i = (long)blockIdx.x * blockDim.x + threadIdx.x;
  long stride = (long)gridDim.x * blockDim.x;
  for (; i < n8; i += stride) {
    const float4* p = (const float4*)(x + i * 8);
    float4 a = p[0], b = p[1];
    u16x8 r;
    r[0] = f2bf(a.x); r[1] = f2bf(a.y); r[2] = f2bf(a.z); r[3] = f2bf(a.w);
    r[4] = f2bf(b.x); r[5] = f2bf(b.y); r[6] = f2bf(b.z); r[7] = f2bf(b.w);
    *(u16x8*)(o + i * 8) = r;
  }
}

// packed_weight arrives as int32 (harness widens uint8 -> int): one packed
// byte (two 4-bit rows) per int element. Row stride = IN_F ints.
__global__ void dequant_w_kernel(const int* __restrict__ pw,
                                 const float* __restrict__ sp,
                                 const float* __restrict__ zpp,
                                 unsigned short* __restrict__ W) {
  const float scale = *sp, zp = *zpp;
  int i = blockIdx.x * blockDim.x + threadIdx.x;   // one 8-byte packed chunk
  const int total = (OUT_F / 2) * (IN_F / 8);
  if (i >= total) return;
  int r = i / (IN_F / 8);
  int c = (i - r * (IN_F / 8)) * 8;
  const int* src = pw + (size_t)r * IN_F + c;
  int4 p0 = *(const int4*)(src);
  int4 p1 = *(const int4*)(src + 4);
  int bytes[8] = { p0.x, p0.y, p0.z, p0.w, p1.x, p1.y, p1.z, p1.w };
  u16x8 lo, hi;
#pragma unroll
  for (int j = 0; j < 8; ++j) {
    unsigned int b = (unsigned int)bytes[j] & 0xFFu;
    lo[j] = f2bf(scale * ((float)(b & 15u) - zp));
    hi[j] = f2bf(scale * ((float)(b >> 4) - zp));
  }
  // packed row r -> W rows 2r (low nibble) and 2r+1 (high nibble)
  *(u16x8*)(W + (size_t)(2 * r) * IN_F + c) = lo;
  *(u16x8*)(W + (size_t)(2 * r + 1) * IN_F + c) = hi;
}

// ---------------- GEMM: C[M][N] = A[M][K] * B[N][K]^T + bias ----------------
// 128x128 tile, BK=64, 256 threads = 4 waves (2x2), each wave owns 64x64
// (4x4 grid of 16x16x32 bf16 MFMA fragments). m97-class 2-barrier structure.

template <bool XB16, bool WB16>
__global__ __launch_bounds__(256)
void gemm_kernel(const unsigned short* __restrict__ Abf,
                 const float* __restrict__ Af32,
                 const unsigned short* __restrict__ Bbf,
                 const int* __restrict__ Bpk,
                 const float* __restrict__ sp,
                 const float* __restrict__ zpp,
                 const float* __restrict__ bias,
                 float* __restrict__ C, int M, int N, int K)
{
  __shared__ unsigned short sA[BM * BK];
  __shared__ unsigned short sB[BN * BK];

  const int tid  = threadIdx.x;
  const int lane = tid & 63;
  const int wid  = tid >> 6;
  const int wm = wid >> 1, wn = wid & 1;

  const int ntn = N / BN;
  const int tm = blockIdx.x / ntn, tn = blockIdx.x - tm * ntn;
  const int row0 = tm * BM, col0 = tn * BN;

  float scale = 0.f, zp = 0.f;
  if (!WB16) { scale = *sp; zp = *zpp; }

  f32x4 acc[4][4];
#pragma unroll
  for (int m = 0; m < 4; ++m)
#pragma unroll
    for (int n = 0; n < 4; ++n)
#pragma unroll
      for (int j = 0; j < 4; ++j)
        acc[m][n][j] = 0.0f;

  const int lrow = lane & 15;
  const int lko  = (lane >> 4) * 8;

  for (int k0 = 0; k0 < K; k0 += BK) {
    // ---- stage A tile: sA[r][k] = A[row0+r][k0+k] ----
    if (XB16) {
#pragma unroll
      for (int i = 0; i < 4; ++i) {
        const int wbase = i * 256 + (wid << 6);     // wave-uniform chunk base
        const int c = wbase + lane;
        const int r = c >> 3, ce = (c & 7) * 8;
        gload_lds16(sA + (size_t)wbase * 8,
                    Abf + (size_t)(row0 + r) * K + k0 + ce);
      }
    } else {
#pragma unroll
      for (int i = 0; i < 4; ++i) {
        const int c = i * 256 + tid;
        const int r = c >> 3, ce = (c & 7) * 8;
        const float4* p = (const float4*)(Af32 + (size_t)(row0 + r) * K + k0 + ce);
        float4 a = p[0], b = p[1];
        u16x8 v;
        v[0] = f2bf(a.x); v[1] = f2bf(a.y); v[2] = f2bf(a.z); v[3] = f2bf(a.w);
        v[4] = f2bf(b.x); v[5] = f2bf(b.y); v[6] = f2bf(b.z); v[7] = f2bf(b.w);
        *(u16x8*)(sA + c * 8) = v;
      }
    }
    // ---- stage B tile: sB[r][k] = W[col0+r][k0+k] ----
    if (WB16) {
#pragma unroll
      for (int i = 0; i < 4; ++i) {
        const int wbase = i * 256 + (wid << 6);
        const int c = wbase + lane;
        const int r = c >> 3, ce = (c & 7) * 8;
        gload_lds16(sB + (size_t)wbase * 8,
                    Bbf + (size_t)(col0 + r) * K + k0 + ce);
      }
    } else {
#pragma unroll
      for (int i = 0; i < 4; ++i) {
        const int c = i * 256 + tid;
        const int r = c >> 3, ce = (c & 7) * 8;
        const int ng = col0 + r;
        const int* src = Bpk + (size_t)(ng >> 1) * K + k0 + ce;
        int4 p0 = *(const int4*)(src);
        int4 p1 = *(const int4*)(src + 4);
        int bytes[8] = { p0.x, p0.y, p0.z, p0.w, p1.x, p1.y, p1.z, p1.w };
        const int sh = (ng & 1) * 4;
        u16x8 v;
#pragma unroll
        for (int j = 0; j < 8; ++j) {
          unsigned int b = (((unsigned int)bytes[j]) >> sh) & 0xFu;
          v[j] = f2bf(scale * ((float)b - zp));
        }
        *(u16x8*)(sB + c * 8) = v;
      }
    }

    __syncthreads();

    bf16x8 af[4][2], bfr[4][2];
#pragma unroll
    for (int m = 0; m < 4; ++m) {
      const int r = wm * 64 + m * 16 + lrow;
#pragma unroll
      for (int kk = 0; kk < 2; ++kk)
        af[m][kk] = *(const bf16x8*)(sA + r * BK + kk * 32 + lko);
    }
#pragma unroll
    for (int n = 0; n < 4; ++n) {
      const int r = wn * 64 + n * 16 + lrow;
#pragma unroll
      for (int kk = 0; kk < 2; ++kk)
        bfr[n][kk] = *(const bf16x8*)(sB + r * BK + kk * 32 + lko);
    }
#pragma unroll
    for (int kk = 0; kk < 2; ++kk)
#pragma unroll
      for (int m = 0; m < 4; ++m)
#pragma unroll
        for (int n = 0; n < 4; ++n)
          acc[m][n] = __builtin_amdgcn_mfma_f32_16x16x32_bf16(
              af[m][kk], bfr[n][kk], acc[m][n], 0, 0, 0);

    __syncthreads();
  }

  // ---- epilogue: C = acc + bias ----
  // D layout (16x16): col = lane&15, row = (lane>>4)*4 + j   [guide §3, m89/m91]
#pragma unroll
  for (int n = 0; n < 4; ++n) {
    const int col = col0 + wn * 64 + n * 16 + lrow;
    const float bv = bias[col];
#pragma unroll
    for (int m = 0; m < 4; ++m) {
      const int row = row0 + wm * 64 + m * 16 + (lane >> 4) * 4;
      const f32x4 v = acc[m][n];
#pragma unroll
      for (int j = 0; j < 4; ++j)
        C[(size_t)(row + j) * N + col] = v[j] + bv;
    }
  }
}

// ---------------- host launch ----------------

extern "C" void kernel_launch(void* const* d_in, const int* in_sizes, int n_in,
                              void* d_out, int out_size, void* d_ws, size_t ws_size,
                              hipStream_t stream) {
  const float* x      = (const float*)d_in[0];
  const int* pw       = (const int*)d_in[1];     // uint8 widened to int32 by harness
  const float* scale  = (const float*)d_in[2];
  const float* zp     = (const float*)d_in[3];
  const float* bias   = (const float*)d_in[4];
  float* out = (float*)d_out;

  const int K = IN_F, N = OUT_F;
  const int M = in_sizes[0] / K;                 // 8192

  const size_t xbytes = (size_t)M * K * 2;       // bf16 X: 64 MiB
  const size_t wbytes = (size_t)N * K * 2;       // bf16 W: 32 MiB

  const int grid = (M / BM) * (N / BN);          // 2048 blocks

  if (ws_size >= xbytes + wbytes) {
    unsigned short* Xb = (unsigned short*)d_ws;
    unsigned short* Wb = (unsigned short*)((char*)d_ws + xbytes);
    long n8 = (long)M * K / 8;
    cvt_x_kernel<<<2048, 256, 0, stream>>>(x, Xb, n8);
    dequant_w_kernel<<<(OUT_F / 2) * (IN_F / 8) / 256, 256, 0, stream>>>(pw, scale, zp, Wb);
    gemm_kernel<true, true><<<grid, 256, 0, stream>>>(
        Xb, nullptr, Wb, nullptr, scale, zp, bias, out, M, N, K);
  } else if (ws_size >= wbytes) {
    // ws fits only the dequantized weight; convert x per-tile in-kernel
    unsigned short* Wb = (unsigned short*)d_ws;
    dequant_w_kernel<<<(OUT_F / 2) * (IN_F / 8) / 256, 256, 0, stream>>>(pw, scale, zp, Wb);
    gemm_kernel<false, true><<<grid, 256, 0, stream>>>(
        nullptr, x, Wb, nullptr, scale, zp, bias, out, M, N, K);
  } else {
    // no usable workspace: fully fused fallback (dequant + cvt in staging)
    gemm_kernel<false, false><<<grid, 256, 0, stream>>>(
        nullptr, x, nullptr, pw, scale, zp, bias, out, M, N, K);
  }
}

// Round 3
// 329.431 us; speedup vs baseline: 1.2793x; 1.2793x over previous
//
#include <hip/hip_runtime.h>
#include <stdint.h>

#define IN_F  4096
#define OUT_F 4096

typedef __attribute__((ext_vector_type(8))) short bf16x8;
typedef __attribute__((ext_vector_type(4))) float f32x4;
typedef __attribute__((ext_vector_type(8))) unsigned short u16x8;

__device__ __forceinline__ unsigned short f2bf(float f) {
  union { float f; unsigned int u; } v; v.f = f;
  return (unsigned short)((v.u + 0x7FFFu + ((v.u >> 16) & 1u)) >> 16);
}

__device__ __forceinline__ void gload_lds16(void* lds, const void* g) {
  __builtin_amdgcn_global_load_lds((const __attribute__((address_space(1))) void*)g,
                                   (__attribute__((address_space(3))) void*)lds,
                                   16u, 0, 0u);
}

// ---------------- prep kernels ----------------

__global__ void cvt_x_kernel(const float* __restrict__ x,
                             unsigned short* __restrict__ o, long n8) {
  long i = (long)blockIdx.x * blockDim.x + threadIdx.x;
  long stride = (long)gridDim.x * blockDim.x;
  for (; i < n8; i += stride) {
    const float4* p = (const float4*)(x + i * 8);
    float4 a = p[0], b = p[1];
    u16x8 r;
    r[0] = f2bf(a.x); r[1] = f2bf(a.y); r[2] = f2bf(a.z); r[3] = f2bf(a.w);
    r[4] = f2bf(b.x); r[5] = f2bf(b.y); r[6] = f2bf(b.z); r[7] = f2bf(b.w);
    *(u16x8*)(o + i * 8) = r;
  }
}

// packed_weight arrives as int32 (harness widens uint8 -> int): one packed
// byte (two 4-bit rows) per int element. Row stride = IN_F ints.
__global__ void dequant_w_kernel(const int* __restrict__ pw,
                                 const float* __restrict__ sp,
                                 const float* __restrict__ zpp,
                                 unsigned short* __restrict__ W) {
  const float scale = *sp, zp = *zpp;
  int i = blockIdx.x * blockDim.x + threadIdx.x;   // one 8-byte packed chunk
  const int total = (OUT_F / 2) * (IN_F / 8);
  if (i >= total) return;
  int r = i / (IN_F / 8);
  int c = (i - r * (IN_F / 8)) * 8;
  const int* src = pw + (size_t)r * IN_F + c;
  int4 p0 = *(const int4*)(src);
  int4 p1 = *(const int4*)(src + 4);
  int bytes[8] = { p0.x, p0.y, p0.z, p0.w, p1.x, p1.y, p1.z, p1.w };
  u16x8 lo, hi;
#pragma unroll
  for (int j = 0; j < 8; ++j) {
    unsigned int b = (unsigned int)bytes[j] & 0xFFu;
    lo[j] = f2bf(scale * ((float)(b & 15u) - zp));
    hi[j] = f2bf(scale * ((float)(b >> 4) - zp));
  }
  *(u16x8*)(W + (size_t)(2 * r) * IN_F + c) = lo;
  *(u16x8*)(W + (size_t)(2 * r + 1) * IN_F + c) = hi;
}

// ======================= 256x256 8-phase GEMM (T1+T2+T3+T4+T5) =============
// C[M][N] = A[M][K] * B[N][K]^T + bias. 512 thr = 8 waves (2m x 4n), each
// wave owns 128x64. BK=64, double-buffered 128KiB LDS, st-swizzled (3-bit).
// Stage schedule (derived from last-read times, all >=1 phase after free):
//   P1->b1A0  P2->b1A1  P3->b0B0  P4->b0B1  P5->b0A0  P6->b0A1  P7->b1B0  P8->b1B1
// Counted vmcnt(4) at P4/P8 (covers reads enumerated in journal), never 0 in loop.

#define BAR()   __builtin_amdgcn_s_barrier()
#define FENCE() asm volatile("" ::: "memory")
#define VM(n)   asm volatile("s_waitcnt vmcnt(" #n ")" ::: "memory")

__global__ __launch_bounds__(512, 2)
void gemm256_kernel(const unsigned short* __restrict__ A,
                    const unsigned short* __restrict__ B,
                    const float* __restrict__ bias,
                    float* __restrict__ C, int M, int N, int K)
{
  __shared__ unsigned short sA[2 * 16384];   // [buf][256][64] swizzled
  __shared__ unsigned short sB[2 * 16384];

  const int tid  = threadIdx.x;
  const int lane = tid & 63;
  const int wid  = tid >> 6;          // 0..7
  const int wm   = wid >> 2;          // 0..1
  const int wn   = wid & 3;           // 0..3

  // T1: XCD-aware bijective swizzle (grid % 8 == 0 here: 512 blocks)
  const int cpx = gridDim.x >> 3;
  const int swz = ((int)blockIdx.x & 7) * cpx + ((int)blockIdx.x >> 3);
  const int ntn = N >> 8;
  const int tm = swz / ntn, tn = swz - tm * ntn;
  const int row0 = tm << 8, col0 = tn << 8;

  const int lrow = lane & 15;
  const int ko4  = lane >> 4;               // 0..3
  const int x7   = lrow & 7;
  const int cK0  = ((ko4 ^ x7) << 3);       // swizzled chunk offset, kk=0 (elems)
  const int cK1  = (((4 + ko4) ^ x7) << 3); // kk=1

  // staging: lds chunk q holds logical chunk (q&7)^(row&7) of row q>>3
  const int srow   = tid >> 3;              // 0..63
  const int schunk = (tid & 7) ^ (srow & 7);

  f32x4 acc[8][4];
#pragma unroll
  for (int m = 0; m < 8; ++m)
#pragma unroll
    for (int n = 0; n < 4; ++n)
#pragma unroll
      for (int j = 0; j < 4; ++j) acc[m][n][j] = 0.0f;

  bf16x8 areg[4][2];        // current m-half
  bf16x8 breg[2][2][2];     // [nh][n'][kk] - both n-halves live

#define STAGE_A(buf, h, kt) do {                                              \
    gload_lds16(sA + (buf)*16384 + (h)*8192 + wid*512,                        \
        A + (size_t)((row0 + (h)*128 + srow) * K + (kt)*64 + schunk*8));      \
    gload_lds16(sA + (buf)*16384 + (h)*8192 + 4096 + wid*512,                 \
        A + (size_t)((row0 + (h)*128 + 64 + srow) * K + (kt)*64 + schunk*8)); \
  } while (0)

#define STAGE_B(buf, h, kt) do {                                              \
    gload_lds16(sB + (buf)*16384 + (h)*8192 + wid*512,                        \
        B + (size_t)((col0 + (h)*128 + srow) * K + (kt)*64 + schunk*8));      \
    gload_lds16(sB + (buf)*16384 + (h)*8192 + 4096 + wid*512,                 \
        B + (size_t)((col0 + (h)*128 + 64 + srow) * K + (kt)*64 + schunk*8)); \
  } while (0)

#define LDA_HALF(buf, mh) do {                                                \
    _Pragma("unroll")                                                         \
    for (int m2 = 0; m2 < 4; ++m2) {                                          \
      const int off_ = (buf)*16384 + (wm*128 + (mh)*64 + m2*16 + lrow)*64;    \
      areg[m2][0] = *(const bf16x8*)(sA + off_ + cK0);                        \
      areg[m2][1] = *(const bf16x8*)(sA + off_ + cK1);                        \
    } } while (0)

#define LDB_HALF(buf, nh) do {                                                \
    _Pragma("unroll")                                                         \
    for (int n2 = 0; n2 < 2; ++n2) {                                          \
      const int off_ = (buf)*16384 + (wn*64 + (nh)*32 + n2*16 + lrow)*64;     \
      breg[nh][n2][0] = *(const bf16x8*)(sB + off_ + cK0);                    \
      breg[nh][n2][1] = *(const bf16x8*)(sB + off_ + cK1);                    \
    } } while (0)

#define MFMA_Q(mh, nh) do {                                                   \
    __builtin_amdgcn_s_setprio(1);                                            \
    _Pragma("unroll")                                                         \
    for (int m2 = 0; m2 < 4; ++m2)                                            \
      _Pragma("unroll")                                                       \
      for (int n2 = 0; n2 < 2; ++n2) {                                        \
        acc[(mh)*4+m2][(nh)*2+n2] = __builtin_amdgcn_mfma_f32_16x16x32_bf16(  \
            areg[m2][0], breg[nh][n2][0], acc[(mh)*4+m2][(nh)*2+n2], 0,0,0);  \
        acc[(mh)*4+m2][(nh)*2+n2] = __builtin_amdgcn_mfma_f32_16x16x32_bf16(  \
            areg[m2][1], breg[nh][n2][1], acc[(mh)*4+m2][(nh)*2+n2], 0,0,0);  \
      }                                                                       \
    __builtin_amdgcn_s_setprio(0);                                            \
  } while (0)

  // ---- prologue: tile0 -> buf0 (full), tile1 -> buf1 (B halves only;
  //      A halves of tile1 are staged at P1/P2 of iteration 0) ----
  STAGE_A(0, 0, 0); STAGE_A(0, 1, 0);
  STAGE_B(0, 0, 0); STAGE_B(0, 1, 0);
  STAGE_B(1, 0, 1); STAGE_B(1, 1, 1);
  VM(4);            // buf0 fully landed; tile1's B halves (4 loads) in flight
  BAR(); FENCE();

  const int nkt = K >> 6;               // 64 K-tiles
  const int nit = nkt >> 1;             // 32 iterations
  for (int it = 0; it < nit; ++it) {
    const int t1  = 2 * it + 1;
    const int tn2 = (2 * it + 2 < nkt) ? 2 * it + 2 : nkt - 1;  // clamped: lands
    const int tn3 = (2 * it + 3 < nkt) ? 2 * it + 3 : nkt - 1;  // after last read
    // P1
    LDA_HALF(0, 0); LDB_HALF(0, 0);
    STAGE_A(1, 0, t1);
    BAR(); MFMA_Q(0, 0); BAR(); FENCE();
    // P2
    LDB_HALF(0, 1);
    STAGE_A(1, 1, t1);
    BAR(); MFMA_Q(0, 1); BAR(); FENCE();
    // P3
    LDA_HALF(0, 1);
    STAGE_B(0, 0, tn2);
    BAR(); MFMA_Q(1, 0); BAR(); FENCE();
    // P4
    STAGE_B(0, 1, tn2);
    VM(4);
    BAR(); MFMA_Q(1, 1); BAR(); FENCE();
    // P5
    LDA_HALF(1, 0); LDB_HALF(1, 0);
    STAGE_A(0, 0, tn2);
    BAR(); MFMA_Q(0, 0); BAR(); FENCE();
    // P6
    LDB_HALF(1, 1);
    STAGE_A(0, 1, tn2);
    BAR(); MFMA_Q(0, 1); BAR(); FENCE();
    // P7
    LDA_HALF(1, 1);
    STAGE_B(1, 0, tn3);
    BAR(); MFMA_Q(1, 0); BAR(); FENCE();
    // P8
    STAGE_B(1, 1, tn3);
    VM(4);
    BAR(); MFMA_Q(1, 1); BAR(); FENCE();
  }

  asm volatile("s_waitcnt vmcnt(0)" ::: "memory");  // drain trailing stages

  // ---- epilogue ----
#pragma unroll
  for (int n = 0; n < 4; ++n) {
    const int col = col0 + wn * 64 + n * 16 + lrow;
    const float bv = bias[col];
#pragma unroll
    for (int m = 0; m < 8; ++m) {
      const int row = row0 + wm * 128 + m * 16 + ko4 * 4;
      const f32x4 v = acc[m][n];
#pragma unroll
      for (int j = 0; j < 4; ++j)
        C[(size_t)(row + j) * N + col] = v[j] + bv;
    }
  }
#undef STAGE_A
#undef STAGE_B
#undef LDA_HALF
#undef LDB_HALF
#undef MFMA_Q
}

// ---------------- fallback 128x128 GEMM (correctness safety net) ----------

template <bool XB16>
__global__ __launch_bounds__(256)
void gemm_kernel(const unsigned short* __restrict__ Abf,
                 const float* __restrict__ Af32,
                 const unsigned short* __restrict__ Bbf,
                 const float* __restrict__ bias,
                 float* __restrict__ C, int M, int N, int K)
{
  __shared__ unsigned short sA[128 * 64];
  __shared__ unsigned short sB[128 * 64];
  const int tid  = threadIdx.x;
  const int lane = tid & 63;
  const int wid  = tid >> 6;
  const int wm = wid >> 1, wn = wid & 1;
  const int ntn = N / 128;
  const int tm = blockIdx.x / ntn, tn = blockIdx.x - tm * ntn;
  const int row0 = tm * 128, col0 = tn * 128;

  f32x4 acc[4][4];
#pragma unroll
  for (int m = 0; m < 4; ++m)
#pragma unroll
    for (int n = 0; n < 4; ++n)
#pragma unroll
      for (int j = 0; j < 4; ++j) acc[m][n][j] = 0.0f;

  const int lrow = lane & 15;
  const int lko  = (lane >> 4) * 8;

  for (int k0 = 0; k0 < K; k0 += 64) {
    if (XB16) {
#pragma unroll
      for (int i = 0; i < 4; ++i) {
        const int wbase = i * 256 + (wid << 6);
        const int c = wbase + lane;
        const int r = c >> 3, ce = (c & 7) * 8;
        gload_lds16(sA + (size_t)wbase * 8, Abf + (size_t)(row0 + r) * K + k0 + ce);
      }
    } else {
#pragma unroll
      for (int i = 0; i < 4; ++i) {
        const int c = i * 256 + tid;
        const int r = c >> 3, ce = (c & 7) * 8;
        const float4* p = (const float4*)(Af32 + (size_t)(row0 + r) * K + k0 + ce);
        float4 a = p[0], b = p[1];
        u16x8 v;
        v[0] = f2bf(a.x); v[1] = f2bf(a.y); v[2] = f2bf(a.z); v[3] = f2bf(a.w);
        v[4] = f2bf(b.x); v[5] = f2bf(b.y); v[6] = f2bf(b.z); v[7] = f2bf(b.w);
        *(u16x8*)(sA + c * 8) = v;
      }
    }
#pragma unroll
    for (int i = 0; i < 4; ++i) {
      const int wbase = i * 256 + (wid << 6);
      const int c = wbase + lane;
      const int r = c >> 3, ce = (c & 7) * 8;
      gload_lds16(sB + (size_t)wbase * 8, Bbf + (size_t)(col0 + r) * K + k0 + ce);
    }
    __syncthreads();
    bf16x8 af[4][2], bfr[4][2];
#pragma unroll
    for (int m = 0; m < 4; ++m) {
      const int r = wm * 64 + m * 16 + lrow;
#pragma unroll
      for (int kk = 0; kk < 2; ++kk)
        af[m][kk] = *(const bf16x8*)(sA + r * 64 + kk * 32 + lko);
    }
#pragma unroll
    for (int n = 0; n < 4; ++n) {
      const int r = wn * 64 + n * 16 + lrow;
#pragma unroll
      for (int kk = 0; kk < 2; ++kk)
        bfr[n][kk] = *(const bf16x8*)(sB + r * 64 + kk * 32 + lko);
    }
#pragma unroll
    for (int kk = 0; kk < 2; ++kk)
#pragma unroll
      for (int m = 0; m < 4; ++m)
#pragma unroll
        for (int n = 0; n < 4; ++n)
          acc[m][n] = __builtin_amdgcn_mfma_f32_16x16x32_bf16(
              af[m][kk], bfr[n][kk], acc[m][n], 0, 0, 0);
    __syncthreads();
  }
#pragma unroll
  for (int n = 0; n < 4; ++n) {
    const int col = col0 + wn * 64 + n * 16 + lrow;
    const float bv = bias[col];
#pragma unroll
    for (int m = 0; m < 4; ++m) {
      const int row = row0 + wm * 64 + m * 16 + (lane >> 4) * 4;
      const f32x4 v = acc[m][n];
#pragma unroll
      for (int j = 0; j < 4; ++j)
        C[(size_t)(row + j) * N + col] = v[j] + bv;
    }
  }
}

// ---------------- host launch ----------------

extern "C" void kernel_launch(void* const* d_in, const int* in_sizes, int n_in,
                              void* d_out, int out_size, void* d_ws, size_t ws_size,
                              hipStream_t stream) {
  const float* x      = (const float*)d_in[0];
  const int* pw       = (const int*)d_in[1];     // uint8 widened to int32
  const float* scale  = (const float*)d_in[2];
  const float* zp     = (const float*)d_in[3];
  const float* bias   = (const float*)d_in[4];
  float* out = (float*)d_out;

  const int K = IN_F, N = OUT_F;
  const int M = in_sizes[0] / K;                 // 8192

  const size_t xbytes = (size_t)M * K * 2;       // 64 MiB
  const size_t wbytes = (size_t)N * K * 2;       // 32 MiB

  if (ws_size >= xbytes + wbytes && (M & 255) == 0) {
    unsigned short* Xb = (unsigned short*)d_ws;
    unsigned short* Wb = (unsigned short*)((char*)d_ws + xbytes);
    cvt_x_kernel<<<2048, 256, 0, stream>>>(x, Xb, (long)M * K / 8);
    dequant_w_kernel<<<(OUT_F / 2) * (IN_F / 8) / 256, 256, 0, stream>>>(pw, scale, zp, Wb);
    gemm256_kernel<<<(M / 256) * (N / 256), 512, 0, stream>>>(Xb, Wb, bias, out, M, N, K);
  } else if (ws_size >= xbytes + wbytes) {
    unsigned short* Xb = (unsigned short*)d_ws;
    unsigned short* Wb = (unsigned short*)((char*)d_ws + xbytes);
    cvt_x_kernel<<<2048, 256, 0, stream>>>(x, Xb, (long)M * K / 8);
    dequant_w_kernel<<<(OUT_F / 2) * (IN_F / 8) / 256, 256, 0, stream>>>(pw, scale, zp, Wb);
    gemm_kernel<true><<<(M / 128) * (N / 128), 256, 0, stream>>>(
        Xb, nullptr, Wb, bias, out, M, N, K);
  } else {
    unsigned short* Wb = (unsigned short*)d_ws;  // requires >= 32 MiB ws
    dequant_w_kernel<<<(OUT_F / 2) * (IN_F / 8) / 256, 256, 0, stream>>>(pw, scale, zp, Wb);
    gemm_kernel<false><<<(M / 128) * (N / 128), 256, 0, stream>>>(
        nullptr, x, Wb, bias, out, M, N, K);
  }
}